// Round 6
// baseline (1233.884 us; speedup 1.0000x reference)
//
#include <hip/hip_runtime.h>
#include <hip/hip_fp16.h>

#define NN 100000
#define NE 1600000
#define FIN 64
#define HID 128
#define NL 4
#define NG 512
#define FFN 300
#define BN_EPS 1e-5f
#define SCAN_BLK 1024
#define NSCAN ((NN + SCAN_BLK - 1) / SCAN_BLK)   // 98
#define FILLB 256
#define NPFB ((NN + FILLB - 1) / FILLB)          // 391 nodes per fill block

static inline size_t alignup(size_t x) { return (x + 255) & ~(size_t)255; }

struct half8 { __half2 h[4]; };   // 16 B

// ======================= CSR build =======================
__global__ void k_count(const int* __restrict__ col, int* __restrict__ counts) {
    int e = blockIdx.x * 256 + threadIdx.x;
    if (e < NE) atomicAdd(&counts[col[e]], 1);
}

__global__ void k_dinv(const int* __restrict__ counts, float* __restrict__ dinv) {
    int i = blockIdx.x * 256 + threadIdx.x;
    if (i < NN) dinv[i] = rsqrtf((float)(counts[i] + 1));  // +1 self-loop
}

__global__ __launch_bounds__(256) void k_scan1(const int* __restrict__ counts,
                                               int* __restrict__ incl,
                                               int* __restrict__ bsums) {
    __shared__ int s[256];
    int t = threadIdx.x;
    int base = blockIdx.x * SCAN_BLK + t * 4;
    int c[4];
    #pragma unroll
    for (int j = 0; j < 4; ++j) c[j] = (base + j < NN) ? counts[base + j] : 0;
    int tsum = c[0] + c[1] + c[2] + c[3];
    s[t] = tsum;
    __syncthreads();
    for (int off = 1; off < 256; off <<= 1) {
        int v = (t >= off) ? s[t - off] : 0;
        __syncthreads();
        s[t] += v;
        __syncthreads();
    }
    if (t == 255) bsums[blockIdx.x] = s[255];
    int run = s[t] - tsum;  // exclusive across threads
    #pragma unroll
    for (int j = 0; j < 4; ++j) {
        run += c[j];
        if (base + j < NN) incl[base + j] = run;  // inclusive within block
    }
}

__global__ void k_scan2(int* bsums) {  // single block, 128 threads
    __shared__ int s[128];
    int t = threadIdx.x;
    int v = (t < NSCAN) ? bsums[t] : 0;
    s[t] = v;
    __syncthreads();
    for (int off = 1; off < 128; off <<= 1) {
        int u = (t >= off) ? s[t - off] : 0;
        __syncthreads();
        s[t] += u;
        __syncthreads();
    }
    if (t < NSCAN) bsums[t] = s[t] - v;  // exclusive block offsets
}

__global__ void k_scan3(const int* __restrict__ counts, const int* __restrict__ incl,
                        const int* __restrict__ bsums, int* __restrict__ offs,
                        int* __restrict__ ends) {
    int i = blockIdx.x * 256 + threadIdx.x;
    if (i >= NN) return;
    int cnt = counts[i];
    int off = incl[i] - cnt + bsums[i / SCAN_BLK];
    offs[i] = off;
    ends[i] = off + cnt;
}

// block-owned node-range fill: block b owns nodes [b*NPFB, b*NPFB+NPFB);
// streams full edge list coalescedly, scatters src into its own CSR segment
// via LDS cursors (segment is small -> L2-local writes, written back once).
__global__ __launch_bounds__(1024) void k_fill2(const int* __restrict__ row,
                                                const int* __restrict__ col,
                                                const int* __restrict__ offs,
                                                int* __restrict__ csr_src) {
    __shared__ int cur[NPFB];
    int t = threadIdx.x;
    int lo = blockIdx.x * NPFB;
    int hi = lo + NPFB; if (hi > NN) hi = NN;
    int n = hi - lo;
    for (int i = t; i < n; i += 1024) cur[i] = offs[lo + i];
    __syncthreads();
    for (int e = t; e < NE; e += 1024) {
        int c = col[e];
        if (c >= lo && c < hi) {
            int pos = atomicAdd(&cur[c - lo], 1);
            csr_src[pos] = row[e];
        }
    }
}

// ======================= encoder: x[N,64]@W -> h fp16 =======================
__global__ __launch_bounds__(256) void k_enc(const float* __restrict__ x,
                                             const float* __restrict__ W,
                                             const float* __restrict__ b,
                                             __half* __restrict__ h) {
    __shared__ float sW[FIN * HID];
    __shared__ float sx[64 * (FIN + 1)];
    int t = threadIdx.x;
    int row0 = blockIdx.x * 64;
    for (int i = t; i < FIN * HID; i += 256) sW[i] = W[i];
    for (int i = t; i < 64 * FIN; i += 256) {
        int r = i >> 6, k = i & 63;
        sx[r * (FIN + 1) + k] = (row0 + r < NN) ? x[(size_t)(row0 + r) * FIN + k] : 0.0f;
    }
    __syncthreads();
    int tx = t & 15, ty = t >> 4;
    int j0 = tx * 8, r0 = ty * 4;
    float acc[4][8];
    #pragma unroll
    for (int r = 0; r < 4; ++r)
        #pragma unroll
        for (int j = 0; j < 8; ++j) acc[r][j] = 0.0f;
    for (int k = 0; k < FIN; ++k) {
        float xv[4];
        #pragma unroll
        for (int r = 0; r < 4; ++r) xv[r] = sx[(r0 + r) * (FIN + 1) + k];
        float4 w0 = *(const float4*)&sW[k * HID + j0];
        float4 w1 = *(const float4*)&sW[k * HID + j0 + 4];
        float wv[8] = {w0.x, w0.y, w0.z, w0.w, w1.x, w1.y, w1.z, w1.w};
        #pragma unroll
        for (int r = 0; r < 4; ++r)
            #pragma unroll
            for (int j = 0; j < 8; ++j) acc[r][j] += xv[r] * wv[j];
    }
    #pragma unroll
    for (int r = 0; r < 4; ++r) {
        int rowi = row0 + r0 + r;
        if (rowi < NN) {
            half8 o;
            #pragma unroll
            for (int p = 0; p < 4; ++p)
                o.h[p] = __floats2half2_rn(acc[r][2 * p] + b[j0 + 2 * p],
                                           acc[r][2 * p + 1] + b[j0 + 2 * p + 1]);
            *(half8*)&h[(size_t)rowi * HID + j0] = o;
        }
    }
}

// ==== layer GEMM: hw_scaled = dinv[row] * (h(fp16)[N,128] @ W(fp32)) -> fp16 ====
// activation tile stored transposed sxT[k][row] -> inner loop reads 1 float4
__global__ __launch_bounds__(256) void k_gemm128(const __half* __restrict__ h,
                                                 const float* __restrict__ W,
                                                 const float* __restrict__ dinv,
                                                 __half* __restrict__ hw) {
    __shared__ float sW[64 * HID];           // 32 KB, K-chunk of 64
    __shared__ float sxT[HID][65];           // 33 KB, transposed activations
    int t = threadIdx.x;
    int row0 = blockIdx.x * 64;
    // load 64 rows x 128 halves; 4 halves (8 B) per thread-iteration, store transposed
    for (int i = t; i < 64 * 32; i += 256) {
        int r = i >> 5, c4 = (i & 31) * 4;
        float v0 = 0.0f, v1 = 0.0f, v2 = 0.0f, v3 = 0.0f;
        if (row0 + r < NN) {
            float2 raw = *(const float2*)(h + (size_t)(row0 + r) * HID + c4);
            const __half2* ph = (const __half2*)&raw;
            float2 a = __half22float2(ph[0]);
            float2 bb = __half22float2(ph[1]);
            v0 = a.x; v1 = a.y; v2 = bb.x; v3 = bb.y;
        }
        sxT[c4 + 0][r] = v0;
        sxT[c4 + 1][r] = v1;
        sxT[c4 + 2][r] = v2;
        sxT[c4 + 3][r] = v3;
    }
    int tx = t & 15, ty = t >> 4;
    int j0 = tx * 8, r0 = ty * 4;
    float acc[4][8];
    #pragma unroll
    for (int r = 0; r < 4; ++r)
        #pragma unroll
        for (int j = 0; j < 8; ++j) acc[r][j] = 0.0f;
    for (int kk = 0; kk < HID; kk += 64) {
        __syncthreads();
        for (int i = t; i < 64 * HID; i += 256) sW[i] = W[kk * HID + i];
        __syncthreads();
        for (int k = 0; k < 64; ++k) {
            float4 xq = *(const float4*)&sxT[kk + k][r0];
            float xv[4] = {xq.x, xq.y, xq.z, xq.w};
            float4 w0 = *(const float4*)&sW[k * HID + j0];
            float4 w1 = *(const float4*)&sW[k * HID + j0 + 4];
            float wv[8] = {w0.x, w0.y, w0.z, w0.w, w1.x, w1.y, w1.z, w1.w};
            #pragma unroll
            for (int r = 0; r < 4; ++r)
                #pragma unroll
                for (int j = 0; j < 8; ++j) acc[r][j] += xv[r] * wv[j];
        }
    }
    #pragma unroll
    for (int r = 0; r < 4; ++r) {
        int rowi = row0 + r0 + r;
        if (rowi < NN) {
            float dv = dinv[rowi];
            half8 o;
            #pragma unroll
            for (int p = 0; p < 4; ++p)
                o.h[p] = __floats2half2_rn(dv * acc[r][2 * p], dv * acc[r][2 * p + 1]);
            *(half8*)&hw[(size_t)rowi * HID + j0] = o;
        }
    }
}

// == fused gather + self-loop + bias + BN + ReLU + residual (pre-scaled fp16 rows) ==
// h_agg[c] = dinv[c] * (sum_{r in N(c)} hw[r] + hw[c]);  one wave per node
__global__ __launch_bounds__(256) void k_gather(
    const int* __restrict__ offs, const int* __restrict__ ends,
    const int* __restrict__ csr_src,
    const float* __restrict__ dinv,
    const __half* __restrict__ hw, const __half* __restrict__ hprev,
    const float* __restrict__ bias, const float* __restrict__ gamma,
    const float* __restrict__ beta, const float* __restrict__ mean,
    const float* __restrict__ var,
    __half* __restrict__ hout, int with_res) {
    int node = (blockIdx.x * 256 + threadIdx.x) >> 6;
    if (node >= NN) return;
    int lane = threadIdx.x & 63;
    int d0 = lane * 2;
    int s = offs[node], e = ends[node];
    float a0 = 0.0f, a1 = 0.0f;
    int j = s;
    for (; j + 3 < e; j += 4) {  // 4-deep for load overlap
        int s0 = csr_src[j], s1 = csr_src[j + 1], s2 = csr_src[j + 2], s3 = csr_src[j + 3];
        float2 v0 = __half22float2(*(const __half2*)(hw + (size_t)s0 * HID + d0));
        float2 v1 = __half22float2(*(const __half2*)(hw + (size_t)s1 * HID + d0));
        float2 v2 = __half22float2(*(const __half2*)(hw + (size_t)s2 * HID + d0));
        float2 v3 = __half22float2(*(const __half2*)(hw + (size_t)s3 * HID + d0));
        a0 += v0.x + v1.x + v2.x + v3.x;
        a1 += v0.y + v1.y + v2.y + v3.y;
    }
    for (; j < e; ++j) {
        int s0 = csr_src[j];
        float2 v0 = __half22float2(*(const __half2*)(hw + (size_t)s0 * HID + d0));
        a0 += v0.x;
        a1 += v0.y;
    }
    // self-loop (pre-scaled row) then final dinv[c] scale
    float2 hv = __half22float2(*(const __half2*)(hw + (size_t)node * HID + d0));
    float dc = dinv[node];
    a0 = dc * (a0 + hv.x);
    a1 = dc * (a1 + hv.y);
    // bias + BN + ReLU (+ residual)
    float o0 = a0 + bias[d0 + 0];
    float o1 = a1 + bias[d0 + 1];
    o0 = (o0 - mean[d0 + 0]) * rsqrtf(var[d0 + 0] + BN_EPS) * gamma[d0 + 0] + beta[d0 + 0];
    o1 = (o1 - mean[d0 + 1]) * rsqrtf(var[d0 + 1] + BN_EPS) * gamma[d0 + 1] + beta[d0 + 1];
    o0 = fmaxf(o0, 0.0f);
    o1 = fmaxf(o1, 0.0f);
    if (with_res) {
        float2 p = __half22float2(*(const __half2*)(hprev + (size_t)node * HID + d0));
        o0 += p.x;
        o1 += p.y;
    }
    *(__half2*)(hout + (size_t)node * HID + d0) = __floats2half2_rn(o0, o1);
}

// ======================= pool (segmented, batch sorted, no atomics) =======================
__device__ __forceinline__ int lower_bound_dev(const int* __restrict__ a, int n, int v) {
    int lo = 0, hi = n;
    while (lo < hi) {
        int m = (lo + hi) >> 1;
        if (a[m] < v) lo = m + 1; else hi = m;
    }
    return lo;
}

// one block (256 thr) per graph: thread t owns feature t&127, half t>>7
__global__ __launch_bounds__(256) void k_pool_seg(const __half* __restrict__ h,
                                                  const int* __restrict__ batch,
                                                  float* __restrict__ gfeat) {
    __shared__ int range[2];
    __shared__ float s[256];
    int g = blockIdx.x, t = threadIdx.x;
    if (t == 0) {
        range[0] = lower_bound_dev(batch, NN, g);
        range[1] = lower_bound_dev(batch, NN, g + 1);
    }
    __syncthreads();
    int start = range[0], end = range[1];
    int f = t & 127, half = t >> 7;
    float acc = 0.0f;
    for (int i = start + half; i < end; i += 2)
        acc += __half2float(h[(size_t)i * HID + f]);
    s[t] = acc;
    __syncthreads();
    if (t < 128) {
        float sum = s[t] + s[t + 128];
        float cnt = (float)(end - start);
        gfeat[(size_t)g * HID + t] = sum / fmaxf(cnt, 1.0f);
    }
}

// ======================= MLP =======================
__global__ void k_mlp0(const float* __restrict__ gfeat,
                       const float* __restrict__ W, const float* __restrict__ b,
                       float* __restrict__ out) {
    __shared__ float srow[HID];
    int g = blockIdx.x, t = threadIdx.x;  // 128 threads
    if (t < HID) srow[t] = gfeat[(size_t)g * HID + t];
    __syncthreads();
    for (int j = t; j < FFN; j += 128) {
        float acc = b[j];
        for (int k = 0; k < HID; ++k) acc += srow[k] * W[k * FFN + j];
        out[(size_t)g * FFN + j] = fmaxf(acc, 0.0f);
    }
}

__global__ void k_mlp1(const float* __restrict__ in, const float* __restrict__ W,
                       const float* __restrict__ b, float* __restrict__ out) {
    __shared__ float srow[FFN];
    int g = blockIdx.x, t = threadIdx.x;  // 128 threads
    for (int k = t; k < FFN; k += 128) srow[k] = in[(size_t)g * FFN + k];
    __syncthreads();
    for (int j = t; j < FFN; j += 128) {
        float acc = b[j];
        for (int k = 0; k < FFN; ++k) acc += srow[k] * W[k * FFN + j];
        out[(size_t)g * FFN + j] = fmaxf(acc, 0.0f);
    }
}

__global__ void k_mlp2(const float* __restrict__ in, const float* __restrict__ W,
                       const float* __restrict__ b, float* __restrict__ out) {
    int g = blockIdx.x, lane = threadIdx.x;  // 64 threads
    float acc = 0.0f;
    for (int k = lane; k < FFN; k += 64) acc += in[(size_t)g * FFN + k] * W[k];
    for (int off = 32; off > 0; off >>= 1) acc += __shfl_down(acc, off);
    if (lane == 0) out[g] = acc + b[0];
}

extern "C" void kernel_launch(void* const* d_in, const int* in_sizes, int n_in,
                              void* d_out, int out_size, void* d_ws, size_t ws_size,
                              hipStream_t stream) {
    const float* x    = (const float*)d_in[0];
    const int*   ei   = (const int*)d_in[1];    // [2,E]: rows then cols
    const int*   batch= (const int*)d_in[2];
    const float* encW = (const float*)d_in[3];
    const float* encb = (const float*)d_in[4];
    const float* Ws   = (const float*)d_in[5];
    const float* bs   = (const float*)d_in[6];
    const float* gam  = (const float*)d_in[7];
    const float* bet  = (const float*)d_in[8];
    const float* mean = (const float*)d_in[9];
    const float* var  = (const float*)d_in[10];
    const float* W0   = (const float*)d_in[11];
    const float* b0   = (const float*)d_in[12];
    const float* W1   = (const float*)d_in[13];
    const float* b1   = (const float*)d_in[14];
    const float* W2   = (const float*)d_in[15];
    const float* b2   = (const float*)d_in[16];
    float* out = (float*)d_out;

    char* w = (char*)d_ws;
    float*  dinv    = (float*)w;  w += alignup((size_t)NN * 4);
    int*    counts  = (int*)w;    w += alignup((size_t)NN * 4);
    int*    incl    = (int*)w;    w += alignup((size_t)NN * 4);
    int*    bsums   = (int*)w;    w += alignup((size_t)NSCAN * 4);
    int*    offs    = (int*)w;    w += alignup((size_t)NN * 4);
    int*    ends    = (int*)w;    w += alignup((size_t)NN * 4);
    int*    csr_src = (int*)w;    w += alignup((size_t)NE * 4);
    __half* hA      = (__half*)w; w += alignup((size_t)NN * HID * 2);
    __half* hB      = (__half*)w; w += alignup((size_t)NN * HID * 2);
    __half* hw_     = (__half*)w; w += alignup((size_t)NN * HID * 2);
    float*  gfeat   = (float*)w;  w += alignup((size_t)NG * HID * 4);
    float*  m0      = (float*)w;  w += alignup((size_t)NG * FFN * 4);
    float*  m1      = (float*)w;  w += alignup((size_t)NG * FFN * 4);

    const int* row = ei;
    const int* col = ei + NE;

    // ---- CSR build (per launch; deterministic work) ----
    hipMemsetAsync(counts, 0, (size_t)NN * 4, stream);
    k_count<<<(NE + 255) / 256, 256, 0, stream>>>(col, counts);
    k_dinv<<<(NN + 255) / 256, 256, 0, stream>>>(counts, dinv);
    k_scan1<<<NSCAN, 256, 0, stream>>>(counts, incl, bsums);
    k_scan2<<<1, 128, 0, stream>>>(bsums);
    k_scan3<<<(NN + 255) / 256, 256, 0, stream>>>(counts, incl, bsums, offs, ends);
    k_fill2<<<FILLB, 1024, 0, stream>>>(row, col, offs, csr_src);

    // ---- encoder ----
    k_enc<<<(NN + 63) / 64, 256, 0, stream>>>(x, encW, encb, hA);

    __half* hcur = hA;
    __half* hnext = hB;
    for (int l = 0; l < NL; ++l) {
        k_gemm128<<<(NN + 63) / 64, 256, 0, stream>>>(hcur, Ws + (size_t)l * HID * HID, dinv, hw_);
        k_gather<<<(NN * 64 + 255) / 256, 256, 0, stream>>>(
            offs, ends, csr_src, dinv, hw_, hcur,
            bs + l * HID, gam + l * HID, bet + l * HID, mean + l * HID, var + l * HID,
            hnext, l > 0 ? 1 : 0);
        __half* tmp = hcur; hcur = hnext; hnext = tmp;
    }

    // ---- pool + MLP ----
    k_pool_seg<<<NG, 256, 0, stream>>>(hcur, batch, gfeat);
    k_mlp0<<<NG, 128, 0, stream>>>(gfeat, W0, b0, m0);
    k_mlp1<<<NG, 128, 0, stream>>>(m0, W1, b1, m1);
    k_mlp2<<<NG, 64, 0, stream>>>(m1, W2, b2, out);
}

// Round 7
// 731.023 us; speedup vs baseline: 1.6879x; 1.6879x over previous
//
#include <hip/hip_runtime.h>
#include <hip/hip_fp16.h>

#define NN 100000
#define NE 1600000
#define FIN 64
#define HID 128
#define NL 4
#define NG 512
#define FFN 300
#define BN_EPS 1e-5f
#define SCAN_BLK 1024
#define NSCAN ((NN + SCAN_BLK - 1) / SCAN_BLK)   // 98
#define LDH 136   // padded LDS stride in halves (272 B -> <=2-way bank aliasing)

static inline size_t alignup(size_t x) { return (x + 255) & ~(size_t)255; }

struct half8 { __half2 h[4]; };   // 16 B

typedef _Float16 f16;
typedef __attribute__((ext_vector_type(8))) _Float16 f16x8;
typedef __attribute__((ext_vector_type(4))) float f32x4;

// ======================= CSR build =======================
__global__ void k_count(const int* __restrict__ col, int* __restrict__ counts) {
    int e = blockIdx.x * 256 + threadIdx.x;
    if (e < NE) atomicAdd(&counts[col[e]], 1);
}

__global__ void k_dinv(const int* __restrict__ counts, float* __restrict__ dinv) {
    int i = blockIdx.x * 256 + threadIdx.x;
    if (i < NN) dinv[i] = rsqrtf((float)(counts[i] + 1));  // +1 self-loop
}

__global__ __launch_bounds__(256) void k_scan1(const int* __restrict__ counts,
                                               int* __restrict__ incl,
                                               int* __restrict__ bsums) {
    __shared__ int s[256];
    int t = threadIdx.x;
    int base = blockIdx.x * SCAN_BLK + t * 4;
    int c[4];
    #pragma unroll
    for (int j = 0; j < 4; ++j) c[j] = (base + j < NN) ? counts[base + j] : 0;
    int tsum = c[0] + c[1] + c[2] + c[3];
    s[t] = tsum;
    __syncthreads();
    for (int off = 1; off < 256; off <<= 1) {
        int v = (t >= off) ? s[t - off] : 0;
        __syncthreads();
        s[t] += v;
        __syncthreads();
    }
    if (t == 255) bsums[blockIdx.x] = s[255];
    int run = s[t] - tsum;  // exclusive across threads
    #pragma unroll
    for (int j = 0; j < 4; ++j) {
        run += c[j];
        if (base + j < NN) incl[base + j] = run;  // inclusive within block
    }
}

__global__ void k_scan2(int* bsums) {  // single block, 128 threads
    __shared__ int s[128];
    int t = threadIdx.x;
    int v = (t < NSCAN) ? bsums[t] : 0;
    s[t] = v;
    __syncthreads();
    for (int off = 1; off < 128; off <<= 1) {
        int u = (t >= off) ? s[t - off] : 0;
        __syncthreads();
        s[t] += u;
        __syncthreads();
    }
    if (t < NSCAN) bsums[t] = s[t] - v;  // exclusive block offsets
}

__global__ void k_scan3(const int* __restrict__ counts, const int* __restrict__ incl,
                        const int* __restrict__ bsums, int* __restrict__ offs,
                        int* __restrict__ cursor) {
    int i = blockIdx.x * 256 + threadIdx.x;
    if (i >= NN) return;
    int off = incl[i] - counts[i] + bsums[i / SCAN_BLK];
    offs[i] = off;
    cursor[i] = off;
}

__global__ void k_fill(const int* __restrict__ row, const int* __restrict__ col,
                       int* __restrict__ cursor, int* __restrict__ csr_src) {
    int e = blockIdx.x * 256 + threadIdx.x;
    if (e >= NE) return;
    int r = row[e], c = col[e];
    int pos = atomicAdd(&cursor[c], 1);
    csr_src[pos] = r;
}

// ======================= encoder: x[N,64]@W -> h fp16 =======================
__global__ __launch_bounds__(256) void k_enc(const float* __restrict__ x,
                                             const float* __restrict__ W,
                                             const float* __restrict__ b,
                                             __half* __restrict__ h) {
    __shared__ float sW[FIN * HID];
    __shared__ float sx[64 * (FIN + 1)];
    int t = threadIdx.x;
    int row0 = blockIdx.x * 64;
    for (int i = t; i < FIN * HID; i += 256) sW[i] = W[i];
    for (int i = t; i < 64 * FIN; i += 256) {
        int r = i >> 6, k = i & 63;
        sx[r * (FIN + 1) + k] = (row0 + r < NN) ? x[(size_t)(row0 + r) * FIN + k] : 0.0f;
    }
    __syncthreads();
    int tx = t & 15, ty = t >> 4;
    int j0 = tx * 8, r0 = ty * 4;
    float acc[4][8];
    #pragma unroll
    for (int r = 0; r < 4; ++r)
        #pragma unroll
        for (int j = 0; j < 8; ++j) acc[r][j] = 0.0f;
    for (int k = 0; k < FIN; ++k) {
        float xv[4];
        #pragma unroll
        for (int r = 0; r < 4; ++r) xv[r] = sx[(r0 + r) * (FIN + 1) + k];
        float4 w0 = *(const float4*)&sW[k * HID + j0];
        float4 w1 = *(const float4*)&sW[k * HID + j0 + 4];
        float wv[8] = {w0.x, w0.y, w0.z, w0.w, w1.x, w1.y, w1.z, w1.w};
        #pragma unroll
        for (int r = 0; r < 4; ++r)
            #pragma unroll
            for (int j = 0; j < 8; ++j) acc[r][j] += xv[r] * wv[j];
    }
    #pragma unroll
    for (int r = 0; r < 4; ++r) {
        int rowi = row0 + r0 + r;
        if (rowi < NN) {
            half8 o;
            #pragma unroll
            for (int p = 0; p < 4; ++p)
                o.h[p] = __floats2half2_rn(acc[r][2 * p] + b[j0 + 2 * p],
                                           acc[r][2 * p + 1] + b[j0 + 2 * p + 1]);
            *(half8*)&h[(size_t)rowi * HID + j0] = o;
        }
    }
}

// ==== W preconvert: wt[l][c][k] = (f16) Ws[l][k][c]  (transposed, all layers) ====
__global__ void k_convW(const float* __restrict__ Ws, f16* __restrict__ wt) {
    int tid = blockIdx.x * 256 + threadIdx.x;
    for (int i = tid; i < NL * HID * HID; i += 64 * 256) {
        int l = i >> 14, rem = i & 16383;
        int c = rem >> 7, k = rem & 127;
        wt[i] = (f16)Ws[(l << 14) + k * HID + c];
    }
}

// ==== MFMA layer GEMM: hw = dinv[row] * (h[N,128](f16) @ W[128,128]) -> f16 ====
// block: 256 thr = 4 waves, 64 rows x 128 cols; K=128 fully staged in LDS.
// mfma_f32_16x16x32_f16; A: row=lane&15, k=(lane>>4)*8+i; B: col=lane&15 (same k);
// C/D: col=lane&15, row=(lane>>4)*4+reg.
__global__ __launch_bounds__(256) void k_gemm_mfma(const __half* __restrict__ h,
                                                   const f16* __restrict__ wt,
                                                   const float* __restrict__ dinv,
                                                   __half* __restrict__ hw) {
    __shared__ f16 sh[64 * LDH];    // 17.4 KB
    __shared__ f16 sw[128 * LDH];   // 34.8 KB
    int t = threadIdx.x;
    int row0 = blockIdx.x * 64;
    for (int idx = t; idx < 64 * 16; idx += 256) {
        int r = idx >> 4, ch = (idx & 15) * 8;
        f16x8 v = {0, 0, 0, 0, 0, 0, 0, 0};
        if (row0 + r < NN) v = *(const f16x8*)(h + (size_t)(row0 + r) * HID + ch);
        *(f16x8*)&sh[r * LDH + ch] = v;
    }
    for (int idx = t; idx < 128 * 16; idx += 256) {
        int c = idx >> 4, ch = (idx & 15) * 8;
        *(f16x8*)&sw[c * LDH + ch] = *(const f16x8*)(wt + c * HID + ch);
    }
    __syncthreads();
    int w = t >> 6, lane = t & 63;
    int lrow = lane & 15, lk = (lane >> 4) * 8;
    f32x4 acc[8];
    #pragma unroll
    for (int ct = 0; ct < 8; ++ct) acc[ct] = (f32x4){0.0f, 0.0f, 0.0f, 0.0f};
    const f16* pa = &sh[(w * 16 + lrow) * LDH + lk];
    #pragma unroll
    for (int ks = 0; ks < 4; ++ks) {
        f16x8 a = *(const f16x8*)(pa + ks * 32);
        #pragma unroll
        for (int ct = 0; ct < 8; ++ct) {
            f16x8 b = *(const f16x8*)&sw[(ct * 16 + lrow) * LDH + ks * 32 + lk];
            acc[ct] = __builtin_amdgcn_mfma_f32_16x16x32_f16(a, b, acc[ct], 0, 0, 0);
        }
    }
    int rbase = row0 + w * 16 + (lane >> 4) * 4;
    #pragma unroll
    for (int i = 0; i < 4; ++i) {
        int grow = rbase + i;
        if (grow < NN) {
            float dv = dinv[grow];
            #pragma unroll
            for (int ct = 0; ct < 8; ++ct)
                hw[(size_t)grow * HID + ct * 16 + lrow] = __float2half(dv * acc[ct][i]);
        }
    }
}

// == fused gather + self-loop + bias + BN + ReLU + residual (pre-scaled fp16 rows) ==
// h_agg[c] = dinv[c] * (sum_{r in N(c)} hw[r] + hw[c]);  one wave per node
__global__ __launch_bounds__(256) void k_gather(
    const int* __restrict__ offs, const int* __restrict__ ends,
    const int* __restrict__ csr_src,
    const float* __restrict__ dinv,
    const __half* __restrict__ hw, const __half* __restrict__ hprev,
    const float* __restrict__ bias, const float* __restrict__ gamma,
    const float* __restrict__ beta, const float* __restrict__ mean,
    const float* __restrict__ var,
    __half* __restrict__ hout, int with_res) {
    int node = (blockIdx.x * 256 + threadIdx.x) >> 6;
    if (node >= NN) return;
    int lane = threadIdx.x & 63;
    int d0 = lane * 2;
    int s = offs[node], e = ends[node];
    float a0 = 0.0f, a1 = 0.0f;
    int j = s;
    for (; j + 3 < e; j += 4) {  // 4-deep for load overlap
        int s0 = csr_src[j], s1 = csr_src[j + 1], s2 = csr_src[j + 2], s3 = csr_src[j + 3];
        float2 v0 = __half22float2(*(const __half2*)(hw + (size_t)s0 * HID + d0));
        float2 v1 = __half22float2(*(const __half2*)(hw + (size_t)s1 * HID + d0));
        float2 v2 = __half22float2(*(const __half2*)(hw + (size_t)s2 * HID + d0));
        float2 v3 = __half22float2(*(const __half2*)(hw + (size_t)s3 * HID + d0));
        a0 += v0.x + v1.x + v2.x + v3.x;
        a1 += v0.y + v1.y + v2.y + v3.y;
    }
    for (; j < e; ++j) {
        int s0 = csr_src[j];
        float2 v0 = __half22float2(*(const __half2*)(hw + (size_t)s0 * HID + d0));
        a0 += v0.x;
        a1 += v0.y;
    }
    float2 hv = __half22float2(*(const __half2*)(hw + (size_t)node * HID + d0));
    float dc = dinv[node];
    a0 = dc * (a0 + hv.x);
    a1 = dc * (a1 + hv.y);
    float o0 = a0 + bias[d0 + 0];
    float o1 = a1 + bias[d0 + 1];
    o0 = (o0 - mean[d0 + 0]) * rsqrtf(var[d0 + 0] + BN_EPS) * gamma[d0 + 0] + beta[d0 + 0];
    o1 = (o1 - mean[d0 + 1]) * rsqrtf(var[d0 + 1] + BN_EPS) * gamma[d0 + 1] + beta[d0 + 1];
    o0 = fmaxf(o0, 0.0f);
    o1 = fmaxf(o1, 0.0f);
    if (with_res) {
        float2 p = __half22float2(*(const __half2*)(hprev + (size_t)node * HID + d0));
        o0 += p.x;
        o1 += p.y;
    }
    *(__half2*)(hout + (size_t)node * HID + d0) = __floats2half2_rn(o0, o1);
}

// ======================= pool (segmented, batch sorted, no atomics) =======================
__device__ __forceinline__ int lower_bound_dev(const int* __restrict__ a, int n, int v) {
    int lo = 0, hi = n;
    while (lo < hi) {
        int m = (lo + hi) >> 1;
        if (a[m] < v) lo = m + 1; else hi = m;
    }
    return lo;
}

__global__ __launch_bounds__(256) void k_pool_seg(const __half* __restrict__ h,
                                                  const int* __restrict__ batch,
                                                  float* __restrict__ gfeat) {
    __shared__ int range[2];
    __shared__ float s[256];
    int g = blockIdx.x, t = threadIdx.x;
    if (t == 0) {
        range[0] = lower_bound_dev(batch, NN, g);
        range[1] = lower_bound_dev(batch, NN, g + 1);
    }
    __syncthreads();
    int start = range[0], end = range[1];
    int f = t & 127, half = t >> 7;
    float acc = 0.0f;
    for (int i = start + half; i < end; i += 2)
        acc += __half2float(h[(size_t)i * HID + f]);
    s[t] = acc;
    __syncthreads();
    if (t < 128) {
        float sum = s[t] + s[t + 128];
        float cnt = (float)(end - start);
        gfeat[(size_t)g * HID + t] = sum / fmaxf(cnt, 1.0f);
    }
}

// ======================= MLP =======================
__global__ void k_mlp0(const float* __restrict__ gfeat,
                       const float* __restrict__ W, const float* __restrict__ b,
                       float* __restrict__ out) {
    __shared__ float srow[HID];
    int g = blockIdx.x, t = threadIdx.x;  // 128 threads
    if (t < HID) srow[t] = gfeat[(size_t)g * HID + t];
    __syncthreads();
    for (int j = t; j < FFN; j += 128) {
        float acc = b[j];
        for (int k = 0; k < HID; ++k) acc += srow[k] * W[k * FFN + j];
        out[(size_t)g * FFN + j] = fmaxf(acc, 0.0f);
    }
}

__global__ void k_mlp1(const float* __restrict__ in, const float* __restrict__ W,
                       const float* __restrict__ b, float* __restrict__ out) {
    __shared__ float srow[FFN];
    int g = blockIdx.x, t = threadIdx.x;  // 128 threads
    for (int k = t; k < FFN; k += 128) srow[k] = in[(size_t)g * FFN + k];
    __syncthreads();
    for (int j = t; j < FFN; j += 128) {
        float acc = b[j];
        for (int k = 0; k < FFN; ++k) acc += srow[k] * W[k * FFN + j];
        out[(size_t)g * FFN + j] = fmaxf(acc, 0.0f);
    }
}

__global__ void k_mlp2(const float* __restrict__ in, const float* __restrict__ W,
                       const float* __restrict__ b, float* __restrict__ out) {
    int g = blockIdx.x, lane = threadIdx.x;  // 64 threads
    float acc = 0.0f;
    for (int k = lane; k < FFN; k += 64) acc += in[(size_t)g * FFN + k] * W[k];
    for (int off = 32; off > 0; off >>= 1) acc += __shfl_down(acc, off);
    if (lane == 0) out[g] = acc + b[0];
}

extern "C" void kernel_launch(void* const* d_in, const int* in_sizes, int n_in,
                              void* d_out, int out_size, void* d_ws, size_t ws_size,
                              hipStream_t stream) {
    const float* x    = (const float*)d_in[0];
    const int*   ei   = (const int*)d_in[1];    // [2,E]: rows then cols
    const int*   batch= (const int*)d_in[2];
    const float* encW = (const float*)d_in[3];
    const float* encb = (const float*)d_in[4];
    const float* Ws   = (const float*)d_in[5];
    const float* bs   = (const float*)d_in[6];
    const float* gam  = (const float*)d_in[7];
    const float* bet  = (const float*)d_in[8];
    const float* mean = (const float*)d_in[9];
    const float* var  = (const float*)d_in[10];
    const float* W0   = (const float*)d_in[11];
    const float* b0   = (const float*)d_in[12];
    const float* W1   = (const float*)d_in[13];
    const float* b1   = (const float*)d_in[14];
    const float* W2   = (const float*)d_in[15];
    const float* b2   = (const float*)d_in[16];
    float* out = (float*)d_out;

    char* w = (char*)d_ws;
    float*  dinv    = (float*)w;  w += alignup((size_t)NN * 4);
    int*    counts  = (int*)w;    w += alignup((size_t)NN * 4);
    int*    incl    = (int*)w;    w += alignup((size_t)NN * 4);
    int*    bsums   = (int*)w;    w += alignup((size_t)NSCAN * 4);
    int*    offs    = (int*)w;    w += alignup((size_t)NN * 4);
    int*    cursor  = (int*)w;    w += alignup((size_t)NN * 4);
    int*    csr_src = (int*)w;    w += alignup((size_t)NE * 4);
    __half* hA      = (__half*)w; w += alignup((size_t)NN * HID * 2);
    __half* hB      = (__half*)w; w += alignup((size_t)NN * HID * 2);
    __half* hw_     = (__half*)w; w += alignup((size_t)NN * HID * 2);
    f16*    wt      = (f16*)w;    w += alignup((size_t)NL * HID * HID * 2);
    float*  gfeat   = (float*)w;  w += alignup((size_t)NG * HID * 4);
    float*  m0      = (float*)w;  w += alignup((size_t)NG * FFN * 4);
    float*  m1      = (float*)w;  w += alignup((size_t)NG * FFN * 4);

    const int* row = ei;
    const int* col = ei + NE;

    // ---- CSR build (per launch; deterministic work) ----
    hipMemsetAsync(counts, 0, (size_t)NN * 4, stream);
    k_count<<<(NE + 255) / 256, 256, 0, stream>>>(col, counts);
    k_dinv<<<(NN + 255) / 256, 256, 0, stream>>>(counts, dinv);
    k_scan1<<<NSCAN, 256, 0, stream>>>(counts, incl, bsums);
    k_scan2<<<1, 128, 0, stream>>>(bsums);
    k_scan3<<<(NN + 255) / 256, 256, 0, stream>>>(counts, incl, bsums, offs, cursor);
    k_fill<<<(NE + 255) / 256, 256, 0, stream>>>(row, col, cursor, csr_src);

    // ---- weights preconvert + encoder ----
    k_convW<<<64, 256, 0, stream>>>(Ws, wt);
    k_enc<<<(NN + 63) / 64, 256, 0, stream>>>(x, encW, encb, hA);

    __half* hcur = hA;
    __half* hnext = hB;
    for (int l = 0; l < NL; ++l) {
        k_gemm_mfma<<<(NN + 63) / 64, 256, 0, stream>>>(hcur, wt + (size_t)l * HID * HID, dinv, hw_);
        k_gather<<<(NN * 64 + 255) / 256, 256, 0, stream>>>(
            offs, cursor, csr_src, dinv, hw_, hcur,
            bs + l * HID, gam + l * HID, bet + l * HID, mean + l * HID, var + l * HID,
            hnext, l > 0 ? 1 : 0);
        __half* tmp = hcur; hcur = hnext; hnext = tmp;
    }

    // ---- pool + MLP ----
    k_pool_seg<<<NG, 256, 0, stream>>>(hcur, batch, gfeat);
    k_mlp0<<<NG, 128, 0, stream>>>(gfeat, W0, b0, m0);
    k_mlp1<<<NG, 128, 0, stream>>>(m0, W1, b1, m1);
    k_mlp2<<<NG, 64, 0, stream>>>(m1, W2, b2, out);
}

// Round 8
// 622.437 us; speedup vs baseline: 1.9823x; 1.1745x over previous
//
#include <hip/hip_runtime.h>
#include <hip/hip_fp16.h>

#define NN 100000
#define NE 1600000
#define FIN 64
#define HID 128
#define NL 4
#define NG 512
#define FFN 300
#define BN_EPS 1e-5f
#define LDH 136   // padded LDS stride in halves (272 B -> <=2-way bank aliasing)
#define NB 512    // CSR buckets
#define NPB 196   // nodes per bucket = ceil(NN/NB)
#define CURPAD 16 // bucket cursor padding (one per 64B line)

static inline size_t alignup(size_t x) { return (x + 255) & ~(size_t)255; }

struct half8 { __half2 h[4]; };   // 16 B

typedef _Float16 f16;
typedef __attribute__((ext_vector_type(8))) _Float16 f16x8;
typedef __attribute__((ext_vector_type(4))) float f32x4;

// ======================= CSR build (bucketed, dense writes) =======================
// 1) per-bucket edge counts via LDS histogram
__global__ __launch_bounds__(1024) void k_bcount(const int* __restrict__ col,
                                                 int* __restrict__ bcnt) {
    __shared__ int h[NB];
    int t = threadIdx.x;
    if (t < NB) h[t] = 0;
    __syncthreads();
    for (int e = blockIdx.x * 1024 + t; e < NE; e += 256 * 1024)
        atomicAdd(&h[col[e] / NPB], 1);
    __syncthreads();
    if (t < NB && h[t] > 0) atomicAdd(&bcnt[t], h[t]);
}

// 2) exclusive scan over NB buckets -> bucket CSR/ebuf bases + padded cursors
__global__ void k_bscan(const int* __restrict__ bcnt, int* __restrict__ bbase,
                        int* __restrict__ bcur) {
    __shared__ int s[NB];
    int t = threadIdx.x;  // NB threads
    int v = bcnt[t];
    s[t] = v;
    __syncthreads();
    for (int off = 1; off < NB; off <<= 1) {
        int u = (t >= off) ? s[t - off] : 0;
        __syncthreads();
        s[t] += u;
        __syncthreads();
    }
    int excl = s[t] - v;
    bbase[t] = excl;
    bcur[t * CURPAD] = excl;
    if (t == NB - 1) bbase[NB] = s[t];
}

// 3) scatter (row,col) into bucket-ordered ebuf (monotone positions -> dense lines)
__global__ void k_bscatter(const int* __restrict__ row, const int* __restrict__ col,
                           int* __restrict__ bcur, int2* __restrict__ ebuf) {
    int e = blockIdx.x * 256 + threadIdx.x;
    if (e >= NE) return;
    int c = col[e];
    int pos = atomicAdd(&bcur[(c / NPB) * CURPAD], 1);
    ebuf[pos] = make_int2(row[e], c);
}

// 4) per-bucket: LDS node histogram + scan -> offs/ends/dinv; then LDS-cursor fill
//    into the bucket's contiguous csr_src segment.
__global__ __launch_bounds__(256) void k_binfill(const int2* __restrict__ ebuf,
                                                 const int* __restrict__ bbase,
                                                 int* __restrict__ offs,
                                                 int* __restrict__ ends,
                                                 float* __restrict__ dinv,
                                                 int* __restrict__ csr_src) {
    __shared__ int cnt[NPB];
    __shared__ int scn[256];
    __shared__ int cur[NPB];
    int b = blockIdx.x, t = threadIdx.x;
    int lo = b * NPB;
    int hi = lo + NPB; if (hi > NN) hi = NN;
    int n = hi - lo;
    if (n <= 0) return;   // tail bucket past NN (always 0 edges)
    int s0 = bbase[b], s1 = bbase[b + 1];
    for (int i = t; i < NPB; i += 256) cnt[i] = 0;
    __syncthreads();
    for (int j = s0 + t; j < s1; j += 256)
        atomicAdd(&cnt[ebuf[j].y - lo], 1);
    __syncthreads();
    int v = (t < n) ? cnt[t] : 0;
    scn[t] = v;
    __syncthreads();
    for (int off = 1; off < 256; off <<= 1) {
        int u = (t >= off) ? scn[t - off] : 0;
        __syncthreads();
        scn[t] += u;
        __syncthreads();
    }
    if (t < n) {
        int g = s0 + scn[t] - v;   // global CSR offset of node lo+t
        offs[lo + t] = g;
        ends[lo + t] = g + v;
        dinv[lo + t] = rsqrtf((float)(v + 1));  // +1 self-loop
        cur[t] = g;
    }
    __syncthreads();
    for (int j = s0 + t; j < s1; j += 256) {
        int2 e = ebuf[j];
        int pos = atomicAdd(&cur[e.y - lo], 1);
        csr_src[pos] = e.x;
    }
}

// ======================= encoder: x[N,64]@W -> h fp16 =======================
__global__ __launch_bounds__(256) void k_enc(const float* __restrict__ x,
                                             const float* __restrict__ W,
                                             const float* __restrict__ b,
                                             __half* __restrict__ h) {
    __shared__ float sW[FIN * HID];
    __shared__ float sx[64 * (FIN + 1)];
    int t = threadIdx.x;
    int row0 = blockIdx.x * 64;
    for (int i = t; i < FIN * HID; i += 256) sW[i] = W[i];
    for (int i = t; i < 64 * FIN; i += 256) {
        int r = i >> 6, k = i & 63;
        sx[r * (FIN + 1) + k] = (row0 + r < NN) ? x[(size_t)(row0 + r) * FIN + k] : 0.0f;
    }
    __syncthreads();
    int tx = t & 15, ty = t >> 4;
    int j0 = tx * 8, r0 = ty * 4;
    float acc[4][8];
    #pragma unroll
    for (int r = 0; r < 4; ++r)
        #pragma unroll
        for (int j = 0; j < 8; ++j) acc[r][j] = 0.0f;
    for (int k = 0; k < FIN; ++k) {
        float xv[4];
        #pragma unroll
        for (int r = 0; r < 4; ++r) xv[r] = sx[(r0 + r) * (FIN + 1) + k];
        float4 w0 = *(const float4*)&sW[k * HID + j0];
        float4 w1 = *(const float4*)&sW[k * HID + j0 + 4];
        float wv[8] = {w0.x, w0.y, w0.z, w0.w, w1.x, w1.y, w1.z, w1.w};
        #pragma unroll
        for (int r = 0; r < 4; ++r)
            #pragma unroll
            for (int j = 0; j < 8; ++j) acc[r][j] += xv[r] * wv[j];
    }
    #pragma unroll
    for (int r = 0; r < 4; ++r) {
        int rowi = row0 + r0 + r;
        if (rowi < NN) {
            half8 o;
            #pragma unroll
            for (int p = 0; p < 4; ++p)
                o.h[p] = __floats2half2_rn(acc[r][2 * p] + b[j0 + 2 * p],
                                           acc[r][2 * p + 1] + b[j0 + 2 * p + 1]);
            *(half8*)&h[(size_t)rowi * HID + j0] = o;
        }
    }
}

// ==== W preconvert: wt[l][c][k] = (f16) Ws[l][k][c]  (transposed, all layers) ====
__global__ void k_convW(const float* __restrict__ Ws, f16* __restrict__ wt) {
    int tid = blockIdx.x * 256 + threadIdx.x;
    for (int i = tid; i < NL * HID * HID; i += 64 * 256) {
        int l = i >> 14, rem = i & 16383;
        int c = rem >> 7, k = rem & 127;
        wt[i] = (f16)Ws[(l << 14) + k * HID + c];
    }
}

// ==== MFMA layer GEMM: hw = dinv[row] * (h[N,128](f16) @ W[128,128]) -> f16 ====
__global__ __launch_bounds__(256) void k_gemm_mfma(const __half* __restrict__ h,
                                                   const f16* __restrict__ wt,
                                                   const float* __restrict__ dinv,
                                                   __half* __restrict__ hw) {
    __shared__ f16 sh[64 * LDH];
    __shared__ f16 sw[128 * LDH];
    int t = threadIdx.x;
    int row0 = blockIdx.x * 64;
    for (int idx = t; idx < 64 * 16; idx += 256) {
        int r = idx >> 4, ch = (idx & 15) * 8;
        f16x8 v = {0, 0, 0, 0, 0, 0, 0, 0};
        if (row0 + r < NN) v = *(const f16x8*)(h + (size_t)(row0 + r) * HID + ch);
        *(f16x8*)&sh[r * LDH + ch] = v;
    }
    for (int idx = t; idx < 128 * 16; idx += 256) {
        int c = idx >> 4, ch = (idx & 15) * 8;
        *(f16x8*)&sw[c * LDH + ch] = *(const f16x8*)(wt + c * HID + ch);
    }
    __syncthreads();
    int w = t >> 6, lane = t & 63;
    int lrow = lane & 15, lk = (lane >> 4) * 8;
    f32x4 acc[8];
    #pragma unroll
    for (int ct = 0; ct < 8; ++ct) acc[ct] = (f32x4){0.0f, 0.0f, 0.0f, 0.0f};
    const f16* pa = &sh[(w * 16 + lrow) * LDH + lk];
    #pragma unroll
    for (int ks = 0; ks < 4; ++ks) {
        f16x8 a = *(const f16x8*)(pa + ks * 32);
        #pragma unroll
        for (int ct = 0; ct < 8; ++ct) {
            f16x8 b = *(const f16x8*)&sw[(ct * 16 + lrow) * LDH + ks * 32 + lk];
            acc[ct] = __builtin_amdgcn_mfma_f32_16x16x32_f16(a, b, acc[ct], 0, 0, 0);
        }
    }
    int rbase = row0 + w * 16 + (lane >> 4) * 4;
    #pragma unroll
    for (int i = 0; i < 4; ++i) {
        int grow = rbase + i;
        if (grow < NN) {
            float dv = dinv[grow];
            #pragma unroll
            for (int ct = 0; ct < 8; ++ct)
                hw[(size_t)grow * HID + ct * 16 + lrow] = __float2half(dv * acc[ct][i]);
        }
    }
}

// == fused gather + self-loop + bias + BN + ReLU + residual (pre-scaled fp16 rows) ==
__global__ __launch_bounds__(256) void k_gather(
    const int* __restrict__ offs, const int* __restrict__ ends,
    const int* __restrict__ csr_src,
    const float* __restrict__ dinv,
    const __half* __restrict__ hw, const __half* __restrict__ hprev,
    const float* __restrict__ bias, const float* __restrict__ gamma,
    const float* __restrict__ beta, const float* __restrict__ mean,
    const float* __restrict__ var,
    __half* __restrict__ hout, int with_res) {
    int node = (blockIdx.x * 256 + threadIdx.x) >> 6;
    if (node >= NN) return;
    int lane = threadIdx.x & 63;
    int d0 = lane * 2;
    int s = offs[node], e = ends[node];
    float a0 = 0.0f, a1 = 0.0f;
    int j = s;
    for (; j + 3 < e; j += 4) {
        int s0 = csr_src[j], s1 = csr_src[j + 1], s2 = csr_src[j + 2], s3 = csr_src[j + 3];
        float2 v0 = __half22float2(*(const __half2*)(hw + (size_t)s0 * HID + d0));
        float2 v1 = __half22float2(*(const __half2*)(hw + (size_t)s1 * HID + d0));
        float2 v2 = __half22float2(*(const __half2*)(hw + (size_t)s2 * HID + d0));
        float2 v3 = __half22float2(*(const __half2*)(hw + (size_t)s3 * HID + d0));
        a0 += v0.x + v1.x + v2.x + v3.x;
        a1 += v0.y + v1.y + v2.y + v3.y;
    }
    for (; j < e; ++j) {
        int s0 = csr_src[j];
        float2 v0 = __half22float2(*(const __half2*)(hw + (size_t)s0 * HID + d0));
        a0 += v0.x;
        a1 += v0.y;
    }
    float2 hv = __half22float2(*(const __half2*)(hw + (size_t)node * HID + d0));
    float dc = dinv[node];
    a0 = dc * (a0 + hv.x);
    a1 = dc * (a1 + hv.y);
    float o0 = a0 + bias[d0 + 0];
    float o1 = a1 + bias[d0 + 1];
    o0 = (o0 - mean[d0 + 0]) * rsqrtf(var[d0 + 0] + BN_EPS) * gamma[d0 + 0] + beta[d0 + 0];
    o1 = (o1 - mean[d0 + 1]) * rsqrtf(var[d0 + 1] + BN_EPS) * gamma[d0 + 1] + beta[d0 + 1];
    o0 = fmaxf(o0, 0.0f);
    o1 = fmaxf(o1, 0.0f);
    if (with_res) {
        float2 p = __half22float2(*(const __half2*)(hprev + (size_t)node * HID + d0));
        o0 += p.x;
        o1 += p.y;
    }
    *(__half2*)(hout + (size_t)node * HID + d0) = __floats2half2_rn(o0, o1);
}

// ======================= pool (segmented, batch sorted, no atomics) =======================
__device__ __forceinline__ int lower_bound_dev(const int* __restrict__ a, int n, int v) {
    int lo = 0, hi = n;
    while (lo < hi) {
        int m = (lo + hi) >> 1;
        if (a[m] < v) lo = m + 1; else hi = m;
    }
    return lo;
}

__global__ __launch_bounds__(256) void k_pool_seg(const __half* __restrict__ h,
                                                  const int* __restrict__ batch,
                                                  float* __restrict__ gfeat) {
    __shared__ int range[2];
    __shared__ float s[256];
    int g = blockIdx.x, t = threadIdx.x;
    if (t == 0) {
        range[0] = lower_bound_dev(batch, NN, g);
        range[1] = lower_bound_dev(batch, NN, g + 1);
    }
    __syncthreads();
    int start = range[0], end = range[1];
    int f = t & 127, half = t >> 7;
    float acc = 0.0f;
    for (int i = start + half; i < end; i += 2)
        acc += __half2float(h[(size_t)i * HID + f]);
    s[t] = acc;
    __syncthreads();
    if (t < 128) {
        float sum = s[t] + s[t + 128];
        float cnt = (float)(end - start);
        gfeat[(size_t)g * HID + t] = sum / fmaxf(cnt, 1.0f);
    }
}

// ======================= MLP =======================
__global__ void k_mlp0(const float* __restrict__ gfeat,
                       const float* __restrict__ W, const float* __restrict__ b,
                       float* __restrict__ out) {
    __shared__ float srow[HID];
    int g = blockIdx.x, t = threadIdx.x;  // 128 threads
    if (t < HID) srow[t] = gfeat[(size_t)g * HID + t];
    __syncthreads();
    for (int j = t; j < FFN; j += 128) {
        float acc = b[j];
        for (int k = 0; k < HID; ++k) acc += srow[k] * W[k * FFN + j];
        out[(size_t)g * FFN + j] = fmaxf(acc, 0.0f);
    }
}

__global__ void k_mlp1(const float* __restrict__ in, const float* __restrict__ W,
                       const float* __restrict__ b, float* __restrict__ out) {
    __shared__ float srow[FFN];
    int g = blockIdx.x, t = threadIdx.x;  // 128 threads
    for (int k = t; k < FFN; k += 128) srow[k] = in[(size_t)g * FFN + k];
    __syncthreads();
    for (int j = t; j < FFN; j += 128) {
        float acc = b[j];
        for (int k = 0; k < FFN; ++k) acc += srow[k] * W[k * FFN + j];
        out[(size_t)g * FFN + j] = fmaxf(acc, 0.0f);
    }
}

__global__ void k_mlp2(const float* __restrict__ in, const float* __restrict__ W,
                       const float* __restrict__ b, float* __restrict__ out) {
    int g = blockIdx.x, lane = threadIdx.x;  // 64 threads
    float acc = 0.0f;
    for (int k = lane; k < FFN; k += 64) acc += in[(size_t)g * FFN + k] * W[k];
    for (int off = 32; off > 0; off >>= 1) acc += __shfl_down(acc, off);
    if (lane == 0) out[g] = acc + b[0];
}

extern "C" void kernel_launch(void* const* d_in, const int* in_sizes, int n_in,
                              void* d_out, int out_size, void* d_ws, size_t ws_size,
                              hipStream_t stream) {
    const float* x    = (const float*)d_in[0];
    const int*   ei   = (const int*)d_in[1];    // [2,E]: rows then cols
    const int*   batch= (const int*)d_in[2];
    const float* encW = (const float*)d_in[3];
    const float* encb = (const float*)d_in[4];
    const float* Ws   = (const float*)d_in[5];
    const float* bs   = (const float*)d_in[6];
    const float* gam  = (const float*)d_in[7];
    const float* bet  = (const float*)d_in[8];
    const float* mean = (const float*)d_in[9];
    const float* var  = (const float*)d_in[10];
    const float* W0   = (const float*)d_in[11];
    const float* b0   = (const float*)d_in[12];
    const float* W1   = (const float*)d_in[13];
    const float* b1   = (const float*)d_in[14];
    const float* W2   = (const float*)d_in[15];
    const float* b2   = (const float*)d_in[16];
    float* out = (float*)d_out;

    char* w = (char*)d_ws;
    float*  dinv    = (float*)w;  w += alignup((size_t)NN * 4);
    int*    offs    = (int*)w;    w += alignup((size_t)NN * 4);
    int*    ends    = (int*)w;    w += alignup((size_t)NN * 4);
    int*    csr_src = (int*)w;    w += alignup((size_t)NE * 4);
    int*    bcnt    = (int*)w;    w += alignup((size_t)NB * 4);
    int*    bbase   = (int*)w;    w += alignup((size_t)(NB + 1) * 4);
    int*    bcur    = (int*)w;    w += alignup((size_t)NB * CURPAD * 4);
    int2*   ebuf    = (int2*)w;   w += alignup((size_t)NE * 8);
    __half* hA      = (__half*)w; w += alignup((size_t)NN * HID * 2);
    __half* hB      = (__half*)w; w += alignup((size_t)NN * HID * 2);
    __half* hw_     = (__half*)w; w += alignup((size_t)NN * HID * 2);
    f16*    wt      = (f16*)w;    w += alignup((size_t)NL * HID * HID * 2);
    float*  gfeat   = (float*)w;  w += alignup((size_t)NG * HID * 4);
    float*  m0      = (float*)w;  w += alignup((size_t)NG * FFN * 4);
    float*  m1      = (float*)w;  w += alignup((size_t)NG * FFN * 4);

    const int* row = ei;
    const int* col = ei + NE;

    // ---- CSR build (bucketed; all global writes dense) ----
    hipMemsetAsync(bcnt, 0, (size_t)NB * 4, stream);
    k_bcount<<<256, 1024, 0, stream>>>(col, bcnt);
    k_bscan<<<1, NB, 0, stream>>>(bcnt, bbase, bcur);
    k_bscatter<<<(NE + 255) / 256, 256, 0, stream>>>(row, col, bcur, ebuf);
    k_binfill<<<NB, 256, 0, stream>>>(ebuf, bbase, offs, ends, dinv, csr_src);

    // ---- weights preconvert + encoder ----
    k_convW<<<64, 256, 0, stream>>>(Ws, wt);
    k_enc<<<(NN + 63) / 64, 256, 0, stream>>>(x, encW, encb, hA);

    __half* hcur = hA;
    __half* hnext = hB;
    for (int l = 0; l < NL; ++l) {
        k_gemm_mfma<<<(NN + 63) / 64, 256, 0, stream>>>(hcur, wt + (size_t)l * HID * HID, dinv, hw_);
        k_gather<<<(NN * 64 + 255) / 256, 256, 0, stream>>>(
            offs, ends, csr_src, dinv, hw_, hcur,
            bs + l * HID, gam + l * HID, bet + l * HID, mean + l * HID, var + l * HID,
            hnext, l > 0 ? 1 : 0);
        __half* tmp = hcur; hcur = hnext; hnext = tmp;
    }

    // ---- pool + MLP ----
    k_pool_seg<<<NG, 256, 0, stream>>>(hcur, batch, gfeat);
    k_mlp0<<<NG, 128, 0, stream>>>(gfeat, W0, b0, m0);
    k_mlp1<<<NG, 128, 0, stream>>>(m0, W1, b1, m1);
    k_mlp2<<<NG, 64, 0, stream>>>(m1, W2, b2, out);
}